// Round 5
// baseline (322.248 us; speedup 1.0000x reference)
//
#include <hip/hip_runtime.h>

#define EPSF 1e-6f
#define VB 2048          // vertices per bucket
#define VB_SHIFT 11
#define CHUNK 4096       // edges per chunk
#define NBMAX 256

// K0: pad vertices to float4 for single-line gathers
__global__ __launch_bounds__(256) void pad_kernel(const float* __restrict__ v,
                                                  float4* __restrict__ v4, int N)
{
    int stride = gridDim.x * blockDim.x;
    for (int i = blockIdx.x * blockDim.x + threadIdx.x; i < N; i += stride) {
        size_t b = 3 * (size_t)i;
        v4[i] = make_float4(v[b], v[b + 1], v[b + 2], 0.f);
    }
}

// K1: per-chunk histogram of src buckets
__global__ __launch_bounds__(512) void count_kernel(const int2* __restrict__ edges,
                                                    int* __restrict__ counts,
                                                    int E, int nb)
{
    __shared__ int hist[NBMAX];
    int c = blockIdx.x;
    int base = c * CHUNK;
    int cnt = min(CHUNK, E - base);
    for (int i = threadIdx.x; i < nb; i += 512) hist[i] = 0;
    __syncthreads();
    for (int k = threadIdx.x; k < cnt; k += 512) {
        int src = edges[base + k].x;
        atomicAdd(&hist[src >> VB_SHIFT], 1);
    }
    __syncthreads();
    for (int i = threadIdx.x; i < nb; i += 512) counts[(size_t)c * nb + i] = hist[i];
}

// K2a: per-bucket exclusive scan over chunks (in-place counts -> rel), one wave/bucket
__global__ __launch_bounds__(64) void relscan_kernel(int* __restrict__ counts,
                                                     int* __restrict__ totals,
                                                     int nb, int nchunk)
{
    int b = blockIdx.x;
    int lane = threadIdx.x;
    int running = 0;
    for (int cbase = 0; cbase < nchunk; cbase += 64) {
        int c = cbase + lane;
        int v = (c < nchunk) ? counts[(size_t)c * nb + b] : 0;
        int s = v;
        for (int d = 1; d < 64; d <<= 1) {
            int o = __shfl_up(s, d);
            if (lane >= d) s += o;
        }
        if (c < nchunk) counts[(size_t)c * nb + b] = running + (s - v);
        running += __shfl(s, 63);
    }
    if (lane == 0) totals[b] = running;
}

// K2b: serial scan over bucket totals -> bucketStart[nb+1]
__global__ __launch_bounds__(64) void bstart_kernel(const int* __restrict__ totals,
                                                    int* __restrict__ bucketStart, int nb)
{
    if (threadIdx.x == 0 && blockIdx.x == 0) {
        int run = 0;
        for (int b = 0; b < nb; ++b) { bucketStart[b] = run; run += totals[b]; }
        bucketStart[nb] = run;
    }
}

// K3: weights + LDS counting-sort per chunk, write bucket-contiguous uint2 records
__global__ __launch_bounds__(512) void scatter_kernel(const int2* __restrict__ edges,
    const float4* __restrict__ messages,
    const int* __restrict__ rel,          // [nchunk][nb] exclusive-within-bucket
    const int* __restrict__ bucketStart,  // [nb+1]
    uint2* __restrict__ rec,              // {pack, w bits}
    int E, int nb)
{
    __shared__ unsigned int  s_pack[CHUNK];
    __shared__ float         s_w[CHUNK];
    __shared__ unsigned char s_b[CHUNK];
    __shared__ int hist[NBMAX], lstart[NBMAX], cursor[NBMAX], goff[NBMAX];

    int c = blockIdx.x;
    int base = c * CHUNK;
    int cnt = min(CHUNK, E - base);

    for (int i = threadIdx.x; i < nb; i += 512) hist[i] = 0;
    __syncthreads();

    int2 ed[8]; float wg[8];
#pragma unroll
    for (int j = 0; j < 8; ++j) {
        int k = threadIdx.x + j * 512;
        if (k < cnt) {
            int2 e2 = edges[base + k];
            float4 m0 = messages[2 * (size_t)(base + k)];
            float4 m1 = messages[2 * (size_t)(base + k) + 1];
            ed[j] = e2;
            wg[j] = (((m0.x + m0.y) + (m0.z + m0.w)) +
                     ((m1.x + m1.y) + (m1.z + m1.w))) * 0.125f;
            atomicAdd(&hist[e2.x >> VB_SHIFT], 1);
        }
    }
    __syncthreads();
    if (threadIdx.x == 0) {
        int run = 0;
        for (int b = 0; b < nb; ++b) { lstart[b] = run; cursor[b] = run; run += hist[b]; }
    }
    __syncthreads();
#pragma unroll
    for (int j = 0; j < 8; ++j) {
        int k = threadIdx.x + j * 512;
        if (k < cnt) {
            int b = ed[j].x >> VB_SHIFT;
            int pos = atomicAdd(&cursor[b], 1);
            s_pack[pos] = ((unsigned int)(ed[j].x & (VB - 1)) << 19) | (unsigned int)ed[j].y;
            s_w[pos]    = wg[j];
            s_b[pos]    = (unsigned char)b;
        }
    }
    for (int i = threadIdx.x; i < nb; i += 512)
        goff[i] = bucketStart[i] + rel[(size_t)c * nb + i];
    __syncthreads();
    for (int k = threadIdx.x; k < cnt; k += 512) {
        int b = s_b[k];
        int g = goff[b] + (k - lstart[b]);
        rec[g] = make_uint2(s_pack[k], __float_as_uint(s_w[k]));
    }
}

// K4: per (bucket, slice): LDS accumulation, plain coalesced flush to partial[slice]
template <bool USEV4>
__global__ __launch_bounds__(512) void accum_kernel(
    const float4* __restrict__ vert4,     // padded (USEV4) or null
    const float*  __restrict__ verts,     // raw (fallback)
    const uint2*  __restrict__ rec,
    const int* __restrict__ bucketStart,
    float* __restrict__ partial,          // [nslice][4][N]
    int N, int nslice)
{
    __shared__ float acc[4][VB];   // 32 KB, SoA
    int b = blockIdx.x / nslice;
    int s = blockIdx.x - b * nslice;
    for (int i = threadIdx.x; i < VB; i += 512) {
        acc[0][i] = 0.f; acc[1][i] = 0.f; acc[2][i] = 0.f; acc[3][i] = 0.f;
    }
    __syncthreads();
    int e0 = bucketStart[b], e1 = bucketStart[b + 1];
    int len = e1 - e0;
    int g0 = e0 + (int)((long long)len * s / nslice);
    int g1 = e0 + (int)((long long)len * (s + 1) / nslice);
    int vbase = b << VB_SHIFT;
    for (int g = g0 + threadIdx.x; g < g1; g += 512) {
        uint2 r = rec[g];
        float w = __uint_as_float(r.y);
        int dst = (int)(r.x & 0x7FFFFu);
        int sl  = (int)(r.x >> 19);
        float x0, x1, x2, y0, y1, y2;
        if (USEV4) {
            float4 xv = vert4[vbase + sl];
            float4 yv = vert4[dst];
            x0 = xv.x; x1 = xv.y; x2 = xv.z;
            y0 = yv.x; y1 = yv.y; y2 = yv.z;
        } else {
            const float* xp = verts + 3 * (size_t)(vbase + sl);
            const float* yp = verts + 3 * (size_t)dst;
            x0 = xp[0]; x1 = xp[1]; x2 = xp[2];
            y0 = yp[0]; y1 = yp[1]; y2 = yp[2];
        }
        float t  = x1 * y1 + x2 * y2 - x0 * y0;      // mip(x,y), w=(-1,1,1)
        float v0 = y0 + x0 * t;
        float v1 = y1 + x1 * t;
        float v2 = y2 + x2 * t;
        float vn = sqrtf(v1 * v1 + v2 * v2 - v0 * v0 + EPSF);
        float scale = acoshf(-t) * w / vn;
        atomicAdd(&acc[0][sl], v0 * scale);
        atomicAdd(&acc[1][sl], v1 * scale);
        atomicAdd(&acc[2][sl], v2 * scale);
        atomicAdd(&acc[3][sl], 1.0f);
    }
    __syncthreads();
    float* pb = partial + (size_t)s * 4 * N;
    for (int i = threadIdx.x; i < VB; i += 512) {
        int v = vbase + i;
        if (v < N) {
            pb[v]                 = acc[0][i];
            pb[(size_t)N + v]     = acc[1][i];
            pb[2 * (size_t)N + v] = acc[2][i];
            pb[3 * (size_t)N + v] = acc[3][i];
        }
    }
}

// K5: sum partials, normalize, exp-map
__global__ __launch_bounds__(256) void final_kernel(const float* __restrict__ vertices,
    const float* __restrict__ partial, float* __restrict__ out, int N, int nslice)
{
    int i = blockIdx.x * 256 + threadIdx.x;
    if (i >= N) return;
    float s0 = 0.f, s1 = 0.f, s2 = 0.f, sc = 0.f;
    for (int s = 0; s < nslice; ++s) {
        const float* pb = partial + (size_t)s * 4 * N;
        s0 += pb[i];
        s1 += pb[(size_t)N + i];
        s2 += pb[2 * (size_t)N + i];
        sc += pb[3 * (size_t)N + i];
    }
    float g0 = 0.f, g1 = 0.f, g2 = 0.f;
    if (sc > 0.f) { g0 = s0 / sc; g1 = s1 / sc; g2 = s2 / sc; }
    float an = sqrtf(g1 * g1 + g2 * g2 - g0 * g0 + EPSF);
    float ch = coshf(an);
    float sh = sinhf(an) / an;   // sqrt(K) = 1
    size_t bix = 3 * (size_t)i;
    out[bix + 0] = ch * vertices[bix + 0] + sh * g0;
    out[bix + 1] = ch * vertices[bix + 1] + sh * g1;
    out[bix + 2] = ch * vertices[bix + 2] + sh * g2;
}

// ---------------- fallback path (known-correct, slow) ----------------

__global__ __launch_bounds__(256) void zero_kernel(float4* __restrict__ acc, int n4)
{
    int stride = gridDim.x * blockDim.x;
    for (int i = blockIdx.x * blockDim.x + threadIdx.x; i < n4; i += stride)
        acc[i] = make_float4(0.f, 0.f, 0.f, 0.f);
}

__global__ __launch_bounds__(256) void edge_kernel_dev(const float* __restrict__ vertices,
    const int2* __restrict__ edges, const float4* __restrict__ messages,
    float* __restrict__ acc, int E)
{
    int stride = gridDim.x * blockDim.x;
    for (int e = blockIdx.x * blockDim.x + threadIdx.x; e < E; e += stride) {
        int2 ed = edges[e];
        float4 m0 = messages[2 * e];
        float4 m1 = messages[2 * e + 1];
        float wgt = (((m0.x + m0.y) + (m0.z + m0.w)) +
                     ((m1.x + m1.y) + (m1.z + m1.w))) * 0.125f;
        const float* xp = vertices + 3 * (size_t)ed.x;
        const float* yp = vertices + 3 * (size_t)ed.y;
        float x0 = xp[0], x1 = xp[1], x2 = xp[2];
        float y0 = yp[0], y1 = yp[1], y2 = yp[2];
        float t  = x1 * y1 + x2 * y2 - x0 * y0;
        float v0 = y0 + x0 * t;
        float v1 = y1 + x1 * t;
        float v2 = y2 + x2 * t;
        float vn = sqrtf(v1 * v1 + v2 * v2 - v0 * v0 + EPSF);
        float scale = acoshf(-t) * wgt / vn;
        float* a = acc + 4 * (size_t)ed.x;
        atomicAdd(a + 0, v0 * scale);
        atomicAdd(a + 1, v1 * scale);
        atomicAdd(a + 2, v2 * scale);
        atomicAdd(a + 3, 1.0f);
    }
}

__global__ __launch_bounds__(256) void vertex_kernel_fb(const float* __restrict__ vertices,
    const float4* __restrict__ acc, float* __restrict__ out, int N)
{
    int i = blockIdx.x * blockDim.x + threadIdx.x;
    if (i >= N) return;
    float4 a = acc[i];
    float g0 = 0.f, g1 = 0.f, g2 = 0.f;
    if (a.w > 0.f) { g0 = a.x / a.w; g1 = a.y / a.w; g2 = a.z / a.w; }
    float an = sqrtf(g1 * g1 + g2 * g2 - g0 * g0 + EPSF);
    float ch = coshf(an);
    float sh = sinhf(an) / an;
    size_t bix = 3 * (size_t)i;
    out[bix + 0] = ch * vertices[bix + 0] + sh * g0;
    out[bix + 1] = ch * vertices[bix + 1] + sh * g1;
    out[bix + 2] = ch * vertices[bix + 2] + sh * g2;
}

// ---------------- launch ----------------

extern "C" void kernel_launch(void* const* d_in, const int* in_sizes, int n_in,
                              void* d_out, int out_size, void* d_ws, size_t ws_size,
                              hipStream_t stream)
{
    const float*  vertices = (const float*)d_in[0];
    const int2*   edges    = (const int2*)d_in[1];
    const float4* messages = (const float4*)d_in[2];
    float* out = (float*)d_out;

    int N = in_sizes[0] / 3;   // 500000
    int E = in_sizes[1] / 2;   // 8000000
    int nb = (N + VB - 1) / VB;
    int nchunk = (E + CHUNK - 1) / CHUNK;

    // workspace layout (fixed part)
    size_t off = 0;
    auto alloc = [&](size_t bytes) { size_t o = off; off = (off + bytes + 255) & ~255ull; return o; };
    size_t o_rec = alloc((size_t)E * 8);
    size_t o_cnt = alloc((size_t)nchunk * nb * 4);
    size_t o_tot = alloc((size_t)nb * 4);
    size_t o_bst = alloc((size_t)(nb + 1) * 4);
    size_t fixed = off;

    size_t par_bytes = 4ull * (size_t)N * 4;     // per slice
    size_t v4_bytes  = (size_t)N * 16;

    int nslice = 0; bool usev4 = false;
    if (fixed + v4_bytes + 4 * par_bytes <= ws_size)      { nslice = 4; usev4 = true; }
    else if (fixed + v4_bytes + 2 * par_bytes <= ws_size) { nslice = 2; usev4 = true; }
    else if (fixed + 2 * par_bytes <= ws_size)            { nslice = 2; usev4 = false; }

    if (nb <= NBMAX && (unsigned)N <= (1u << 19) && nslice > 0) {
        char* w = (char*)d_ws;
        uint2* rec   = (uint2*)(w + o_rec);
        int* counts  = (int*)(w + o_cnt);
        int* totals  = (int*)(w + o_tot);
        int* bstart  = (int*)(w + o_bst);
        size_t o2 = fixed;
        float4* v4 = nullptr;
        if (usev4) { v4 = (float4*)(w + o2); o2 += (v4_bytes + 255) & ~255ull; }
        float* partial = (float*)(w + o2);

        if (usev4)
            pad_kernel<<<1024, 256, 0, stream>>>(vertices, v4, N);
        count_kernel<<<nchunk, 512, 0, stream>>>(edges, counts, E, nb);
        relscan_kernel<<<nb, 64, 0, stream>>>(counts, totals, nb, nchunk);
        bstart_kernel<<<1, 64, 0, stream>>>(totals, bstart, nb);
        scatter_kernel<<<nchunk, 512, 0, stream>>>(edges, messages, counts, bstart,
                                                   rec, E, nb);
        if (usev4)
            accum_kernel<true><<<nb * nslice, 512, 0, stream>>>(v4, vertices, rec, bstart,
                                                                partial, N, nslice);
        else
            accum_kernel<false><<<nb * nslice, 512, 0, stream>>>(nullptr, vertices, rec, bstart,
                                                                 partial, N, nslice);
        final_kernel<<<(N + 255) / 256, 256, 0, stream>>>(vertices, partial, out, N, nslice);
    } else {
        // fallback: single-copy device atomics
        float* acc = (float*)d_ws;
        zero_kernel<<<4096, 256, 0, stream>>>((float4*)acc, N);
        edge_kernel_dev<<<4096, 256, 0, stream>>>(vertices, edges, messages, acc, E);
        vertex_kernel_fb<<<(N + 255) / 256, 256, 0, stream>>>(vertices, (const float4*)acc, out, N);
    }
}